// Round 2
// baseline (2588.564 us; speedup 1.0000x reference)
//
#include <hip/hip_runtime.h>
#include <hip/hip_bf16.h>
#include <type_traits>

// ---------------- fixed problem dims ----------------
#define BB   16
#define N0   6273      // 1 + 8*28*28
#define TT   8
#define HH   28
#define WW   28
#define NQ   1569      // 1 + 8*14*14
#define C3   576
#define HID  768
#define DOUT 384
#define M1   (BB*N0)   // 100368
#define M2   (BB*NQ)   // 25104

static __device__ __forceinline__ float bf2f(unsigned short u) {
  return __uint_as_float(((unsigned)u) << 16);
}
static __device__ __forceinline__ unsigned short f2bf(float f) {
  unsigned x = __float_as_uint(f);
  x += 0x7fffu + ((x >> 16) & 1u);   // RNE
  return (unsigned short)(x >> 16);
}

// ---------------- LayerNorm over D=192, one wave per row ----------------
__global__ __launch_bounds__(256) void ln_rows_kernel(
    const float* __restrict__ in, const float* __restrict__ g,
    const float* __restrict__ bta, float* __restrict__ out, int rows) {
  int row = blockIdx.x * 4 + (threadIdx.x >> 6);
  int lane = threadIdx.x & 63;
  if (row >= rows) return;                 // whole wave exits together
  const float* p = in + (size_t)row * 192;
  float v0 = p[lane], v1 = p[lane + 64], v2 = p[lane + 128];
  float s = v0 + v1 + v2;
  float q = v0 * v0 + v1 * v1 + v2 * v2;
  #pragma unroll
  for (int m = 32; m; m >>= 1) { s += __shfl_xor(s, m, 64); q += __shfl_xor(q, m, 64); }
  float mean = s * (1.f / 192.f);
  float var  = q * (1.f / 192.f) - mean * mean;
  float rstd = rsqrtf(var + 1e-5f);
  float* po = out + (size_t)row * 192;
  po[lane]       = (v0 - mean) * rstd * g[lane]       + bta[lane];
  po[lane + 64]  = (v1 - mean) * rstd * g[lane + 64]  + bta[lane + 64];
  po[lane + 128] = (v2 - mean) * rstd * g[lane + 128] + bta[lane + 128];
}

// ---------------- generic tiled GEMM: C[M,N] = act(A[M,K]@B[K,N] + bias) (+C) ----
// TA/TC: float or unsigned short (bf16 bits). B (weights) always fp32 row-major.
template <typename TA, typename TC, int ACT, int BETA>
__global__ __launch_bounds__(256) void gemm_kernel(
    const TA* __restrict__ A, const float* __restrict__ Bw,
    const float* __restrict__ bias, TC* __restrict__ C,
    int M, int Nn, int K) {
  __shared__ float As[16][68];   // [k][m], pad->68 keeps float4 16B-aligned, 2-way max
  __shared__ float Bs[16][68];   // [k][n]
  const int tid = threadIdx.x;
  const int bm = blockIdx.y * 64;
  const int bn = blockIdx.x * 64;
  const int ty = tid >> 4, tx = tid & 15;
  const int r0 = ty * 4, c0 = tx * 4;
  const int la_m = tid >> 2;           // 0..63
  const int la_k = (tid & 3) * 4;      // 0,4,8,12
  const int lb_k = tid >> 4;           // 0..15
  const int lb_n = (tid & 15) * 4;     // 0..60
  float acc[4][4] = {};
  for (int k0 = 0; k0 < K; k0 += 16) {
    float4 av;
    int m = bm + la_m;
    if (m < M) {
      if constexpr (std::is_same<TA, float>::value) {
        av = *reinterpret_cast<const float4*>(A + (size_t)m * K + k0 + la_k);
      } else {
        ushort4 u = *reinterpret_cast<const ushort4*>(
            reinterpret_cast<const unsigned short*>(A) + (size_t)m * K + k0 + la_k);
        av = make_float4(bf2f(u.x), bf2f(u.y), bf2f(u.z), bf2f(u.w));
      }
    } else {
      av = make_float4(0.f, 0.f, 0.f, 0.f);
    }
    float4 bv = *reinterpret_cast<const float4*>(Bw + (size_t)(k0 + lb_k) * Nn + bn + lb_n);
    As[la_k + 0][la_m] = av.x;
    As[la_k + 1][la_m] = av.y;
    As[la_k + 2][la_m] = av.z;
    As[la_k + 3][la_m] = av.w;
    *reinterpret_cast<float4*>(&Bs[lb_k][lb_n]) = bv;
    __syncthreads();
    #pragma unroll
    for (int kk = 0; kk < 16; ++kk) {
      float4 a = *reinterpret_cast<const float4*>(&As[kk][r0]);
      float4 b = *reinterpret_cast<const float4*>(&Bs[kk][c0]);
      float ar[4] = {a.x, a.y, a.z, a.w};
      float br[4] = {b.x, b.y, b.z, b.w};
      #pragma unroll
      for (int i = 0; i < 4; ++i)
        #pragma unroll
        for (int j = 0; j < 4; ++j) acc[i][j] = fmaf(ar[i], br[j], acc[i][j]);
    }
    __syncthreads();
  }
  float bs[4];
  #pragma unroll
  for (int j = 0; j < 4; ++j) bs[j] = bias[bn + c0 + j];
  #pragma unroll
  for (int i = 0; i < 4; ++i) {
    int m = bm + r0 + i;
    if (m >= M) continue;
    #pragma unroll
    for (int j = 0; j < 4; ++j) {
      float v = acc[i][j] + bs[j];
      if (ACT == 1) v = 0.5f * v * (1.f + erff(v * 0.70710678118654752f));  // exact gelu
      size_t oi = (size_t)m * Nn + bn + c0 + j;
      if (BETA) {
        if constexpr (std::is_same<TC, float>::value) v += C[oi];
        else v += bf2f(((const unsigned short*)C)[oi]);
      }
      if constexpr (std::is_same<TC, float>::value) C[oi] = v;
      else ((unsigned short*)C)[oi] = f2bf(v);
    }
  }
}

// ---------------- depthwise conv3d (3x3x3, stride 1,2,2, pad 1) + LN over hd=96 ---
// one block (128 thr) per output row (b, h, l); reads qkv (bf16) laid out [b][n][576]
__global__ __launch_bounds__(128) void pool_ln_kernel(
    const unsigned short* __restrict__ qkv, const float* __restrict__ w,
    const float* __restrict__ g, const float* __restrict__ bb,
    float* __restrict__ outp, int cidx) {
  const int bid = blockIdx.x;
  const int l  = bid % NQ;
  const int bh = bid / NQ;
  const int h  = bh & 1;
  const int b  = bh >> 1;
  const int d  = threadIdx.x;
  __shared__ float red[128];
  __shared__ float stats[2];
  float val = 0.f;
  if (d < 96) {
    const unsigned short* base = qkv + (size_t)b * N0 * C3 + cidx * 192 + h * 96 + d;
    if (l == 0) {
      val = bf2f(base[0]);                          // cls token (n = 0)
    } else {
      int lp = l - 1;
      int to = lp / 196;
      int rem = lp - to * 196;
      int ho = rem / 14;
      int wo = rem - ho * 14;
      const float* wd = w + d * 27;
      #pragma unroll
      for (int kt = 0; kt < 3; ++kt) {
        int it = to + kt - 1;
        if ((unsigned)it >= 8u) continue;
        #pragma unroll
        for (int kh = 0; kh < 3; ++kh) {
          int ih = 2 * ho + kh - 1;
          if ((unsigned)ih >= 28u) continue;
          #pragma unroll
          for (int kw = 0; kw < 3; ++kw) {
            int iw = 2 * wo + kw - 1;
            if ((unsigned)iw >= 28u) continue;
            int n = 1 + (it * 28 + ih) * 28 + iw;
            val += wd[(kt * 3 + kh) * 3 + kw] * bf2f(base[(size_t)n * C3]);
          }
        }
      }
    }
  }
  red[d] = (d < 96) ? val : 0.f;
  __syncthreads();
  for (int s = 64; s > 0; s >>= 1) { if (d < s) red[d] += red[d + s]; __syncthreads(); }
  if (d == 0) stats[0] = red[0] * (1.f / 96.f);
  __syncthreads();
  float mean = stats[0];
  float dv = (d < 96) ? (val - mean) : 0.f;
  red[d] = dv * dv;
  __syncthreads();
  for (int s = 64; s > 0; s >>= 1) { if (d < s) red[d] += red[d + s]; __syncthreads(); }
  if (d == 0) stats[1] = rsqrtf(red[0] * (1.f / 96.f) + 1e-5f);
  __syncthreads();
  if (d < 96)
    outp[((size_t)bh * NQ + l) * 96 + d] = (val - mean) * stats[1] * g[d] + bb[d];
}

// ---------------- flash attention, fp32, QT=64 queries x KC=32 keys per step -----
#define QT 64
#define KC 32
__global__ __launch_bounds__(256) void attn_kernel(
    const float* __restrict__ qp, const float* __restrict__ kp,
    const float* __restrict__ vp, float* __restrict__ o) {
  __shared__ float Qs[QT][97];
  __shared__ float Ks[KC][97];
  __shared__ float Vs[KC][97];
  __shared__ float Ps[QT][KC + 1];
  __shared__ float mrow[QT], lrow[QT], crow[QT];
  const int tid = threadIdx.x;
  const int q0  = blockIdx.x * QT;
  const int bh  = blockIdx.y;
  const float scale = 0.10206207261596577f;  // 1/sqrt(96)
  const float* qb = qp + (size_t)bh * NQ * 96;
  const float* kb = kp + (size_t)bh * NQ * 96;
  const float* vb = vp + (size_t)bh * NQ * 96;

  for (int i = tid; i < QT * 96; i += 256) {
    int r = i / 96, c = i - (i / 96) * 96;
    int qg = q0 + r;
    Qs[r][c] = (qg < NQ) ? qb[(size_t)qg * 96 + c] : 0.f;
  }
  if (tid < QT) { mrow[tid] = -INFINITY; lrow[tid] = 0.f; }
  const int sq0 = (tid >> 4) * 4;       // S tile: 4 q rows
  const int sk0 = (tid & 15) * 2;       //         2 k cols
  const int mq = tid >> 2, mj = tid & 3;  // softmax: 8 elems per thread
  const int pq0 = sq0, pd0 = (tid & 15) * 6;  // PV tile: 4 q x 6 d
  float acc[4][6];
  #pragma unroll
  for (int i = 0; i < 4; ++i)
    #pragma unroll
    for (int j = 0; j < 6; ++j) acc[i][j] = 0.f;
  __syncthreads();

  for (int k0 = 0; k0 < NQ; k0 += KC) {
    for (int i = tid; i < KC * 96; i += 256) {
      int r = i / 96, c = i - (i / 96) * 96;
      int kg = k0 + r;
      if (kg < NQ) {
        Ks[r][c] = kb[(size_t)kg * 96 + c];
        Vs[r][c] = vb[(size_t)kg * 96 + c];
      } else {
        Ks[r][c] = 0.f;
        Vs[r][c] = 0.f;
      }
    }
    __syncthreads();
    // S = Q K^T (scaled), masked for OOB keys
    {
      float s[4][2] = {};
      for (int dd = 0; dd < 96; ++dd) {
        float qv[4], kv[2];
        #pragma unroll
        for (int i = 0; i < 4; ++i) qv[i] = Qs[sq0 + i][dd];
        #pragma unroll
        for (int j = 0; j < 2; ++j) kv[j] = Ks[sk0 + j][dd];
        #pragma unroll
        for (int i = 0; i < 4; ++i)
          #pragma unroll
          for (int j = 0; j < 2; ++j) s[i][j] = fmaf(qv[i], kv[j], s[i][j]);
      }
      #pragma unroll
      for (int j = 0; j < 2; ++j) {
        bool kvalid = (k0 + sk0 + j) < NQ;
        #pragma unroll
        for (int i = 0; i < 4; ++i)
          Ps[sq0 + i][sk0 + j] = kvalid ? s[i][j] * scale : -1e30f;
      }
    }
    __syncthreads();
    // online softmax stats per row (4 lanes per row, same wave)
    {
      float pv[8];
      float mx = -INFINITY;
      #pragma unroll
      for (int e = 0; e < 8; ++e) { pv[e] = Ps[mq][mj * 8 + e]; mx = fmaxf(mx, pv[e]); }
      mx = fmaxf(mx, __shfl_xor(mx, 1, 64));
      mx = fmaxf(mx, __shfl_xor(mx, 2, 64));
      float mold = mrow[mq];
      float mnew = fmaxf(mold, mx);
      float sum = 0.f;
      #pragma unroll
      for (int e = 0; e < 8; ++e) {
        float p = __expf(pv[e] - mnew);
        Ps[mq][mj * 8 + e] = p;
        sum += p;
      }
      sum += __shfl_xor(sum, 1, 64);
      sum += __shfl_xor(sum, 2, 64);
      if (mj == 0) {
        float c = __expf(mold - mnew);   // exp(-inf)=0 on first chunk
        lrow[mq] = lrow[mq] * c + sum;
        crow[mq] = c;
        mrow[mq] = mnew;
      }
    }
    __syncthreads();
    // O = O*c + P V
    {
      #pragma unroll
      for (int i = 0; i < 4; ++i) {
        float c = crow[pq0 + i];
        float s[6];
        #pragma unroll
        for (int j = 0; j < 6; ++j) s[j] = 0.f;
        for (int k = 0; k < KC; ++k) {
          float p = Ps[pq0 + i][k];
          #pragma unroll
          for (int j = 0; j < 6; ++j) s[j] = fmaf(p, Vs[k][pd0 + j], s[j]);
        }
        #pragma unroll
        for (int j = 0; j < 6; ++j) acc[i][j] = acc[i][j] * c + s[j];
      }
    }
    __syncthreads();
  }
  // store: o[b, q, h*96+d] = acc / l
  const int b = bh >> 1, h = bh & 1;
  #pragma unroll
  for (int i = 0; i < 4; ++i) {
    int qg = q0 + pq0 + i;
    if (qg >= NQ) continue;
    float inv = 1.f / lrow[pq0 + i];
    float* po = o + ((size_t)b * NQ + qg) * 192 + h * 96 + pd0;
    #pragma unroll
    for (int j = 0; j < 6; ++j) po[j] = acc[i][j] * inv;
  }
}

// ---------------- maxpool (1,3,3)/(1,2,2)/pad(0,1,1) skip path -> x1 -------------
__global__ __launch_bounds__(256) void maxpool_kernel(
    const float* __restrict__ x, float* __restrict__ x1) {
  int idx = blockIdx.x * 256 + threadIdx.x;
  const int total = BB * NQ * 192;
  if (idx >= total) return;
  int cc = idx % 192;
  int rem = idx / 192;
  int l = rem % NQ;
  int b = rem / NQ;
  const float* xb = x + (size_t)b * N0 * 192;
  float m;
  if (l == 0) {
    m = xb[cc];                       // cls token passthrough
  } else {
    int lp = l - 1;
    int to = lp / 196;
    int r2 = lp - to * 196;
    int ho = r2 / 14;
    int wo = r2 - ho * 14;
    m = -INFINITY;
    #pragma unroll
    for (int kh = 0; kh < 3; ++kh) {
      int ih = 2 * ho + kh - 1;
      if ((unsigned)ih >= 28u) continue;
      #pragma unroll
      for (int kw = 0; kw < 3; ++kw) {
        int iw = 2 * wo + kw - 1;
        if ((unsigned)iw >= 28u) continue;
        int n = 1 + (to * 28 + ih) * 28 + iw;
        m = fmaxf(m, xb[(size_t)n * 192 + cc]);
      }
    }
  }
  x1[idx] = m;
}

// ---------------- launch ----------------
extern "C" void kernel_launch(void* const* d_in, const int* in_sizes, int n_in,
                              void* d_out, int out_size, void* d_ws, size_t ws_size,
                              hipStream_t stream) {
  (void)in_sizes; (void)n_in; (void)out_size; (void)ws_size;
  const float* x       = (const float*)d_in[0];
  const float* ln1_g   = (const float*)d_in[1];
  const float* ln1_b   = (const float*)d_in[2];
  const float* qkv_w   = (const float*)d_in[3];
  const float* qkv_b   = (const float*)d_in[4];
  const float* pq_w    = (const float*)d_in[5];
  const float* pk_w    = (const float*)d_in[6];
  const float* pv_w    = (const float*)d_in[7];
  const float* nq_g    = (const float*)d_in[8];
  const float* nq_b    = (const float*)d_in[9];
  const float* nk_g    = (const float*)d_in[10];
  const float* nk_b    = (const float*)d_in[11];
  const float* nv_g    = (const float*)d_in[12];
  const float* nv_b    = (const float*)d_in[13];
  const float* proj_w  = (const float*)d_in[14];
  const float* proj_b  = (const float*)d_in[15];
  const float* ln2_g   = (const float*)d_in[16];
  const float* ln2_b   = (const float*)d_in[17];
  const float* fc1_w   = (const float*)d_in[18];
  const float* fc1_b   = (const float*)d_in[19];
  const float* fc2_w   = (const float*)d_in[20];
  const float* fc2_b   = (const float*)d_in[21];
  const float* projd_w = (const float*)d_in[22];
  const float* projd_b = (const float*)d_in[23];

  // workspace layout (bytes). Region 1 (xn) and region 2 (qkv) are reused after
  // their producers' consumers finish. Total required: 192,706,560 B (~184 MB).
  char* ws = (char*)d_ws;
  float* xn            = (float*)(ws);                       // 77,082,624 B
  unsigned short* qkvb = (unsigned short*)(ws + 77082624);   // 115,623,936 B
  // region-1 reuse (xn dead after qkv GEMM):
  float* qp = (float*)(ws);
  float* kp = (float*)(ws + 19279872);
  float* vp = (float*)(ws + 38559744);
  // region-2 reuse (qkv dead after pooling):
  char* r2 = ws + 77082624;
  float* ob            = (float*)(r2);
  float* x1            = (float*)(r2 + 19279872);
  float* xn2           = (float*)(r2 + 38559744);
  unsigned short* hmid = (unsigned short*)(r2 + 57839616);
  float* out = (float*)d_out;

  // 1) xn = LN(x)
  ln_rows_kernel<<<(M1 + 3) / 4, 256, 0, stream>>>(x, ln1_g, ln1_b, xn, M1);
  // 2) qkv = xn @ qkv_w + qkv_b   (stored bf16)
  gemm_kernel<float, unsigned short, 0, 0>
      <<<dim3(C3 / 64, (M1 + 63) / 64), 256, 0, stream>>>(xn, qkv_w, qkv_b, qkvb, M1, C3, 192);
  // 3) pooled+LN q, k, v
  pool_ln_kernel<<<BB * 2 * NQ, 128, 0, stream>>>(qkvb, pq_w, nq_g, nq_b, qp, 0);
  pool_ln_kernel<<<BB * 2 * NQ, 128, 0, stream>>>(qkvb, pk_w, nk_g, nk_b, kp, 1);
  pool_ln_kernel<<<BB * 2 * NQ, 128, 0, stream>>>(qkvb, pv_w, nv_g, nv_b, vp, 2);
  // 4) o = softmax(qk^T*scale) v   -> [B, NQ, 192]
  attn_kernel<<<dim3((NQ + QT - 1) / QT, BB * 2), 256, 0, stream>>>(qp, kp, vp, ob);
  // 5) x1 = maxpool_skip(x)
  maxpool_kernel<<<(BB * NQ * 192 + 255) / 256, 256, 0, stream>>>(x, x1);
  // 6) x1 += o @ proj_w + proj_b
  gemm_kernel<float, float, 0, 1>
      <<<dim3(192 / 64, (M2 + 63) / 64), 256, 0, stream>>>(ob, proj_w, proj_b, x1, M2, 192, 192);
  // 7) xn2 = LN(x1)
  ln_rows_kernel<<<(M2 + 3) / 4, 256, 0, stream>>>(x1, ln2_g, ln2_b, xn2, M2);
  // 8) hmid = gelu(xn2 @ fc1_w + fc1_b)   (stored bf16)
  gemm_kernel<float, unsigned short, 1, 0>
      <<<dim3(HID / 64, (M2 + 63) / 64), 256, 0, stream>>>(xn2, fc1_w, fc1_b, hmid, M2, HID, 192);
  // 9) out = hmid @ fc2_w + fc2_b
  gemm_kernel<unsigned short, float, 0, 0>
      <<<dim3(DOUT / 64, (M2 + 63) / 64), 256, 0, stream>>>(hmid, fc2_w, fc2_b, out, M2, DOUT, HID);
  // 10) out += xn2 @ projd_w + projd_b
  gemm_kernel<float, float, 0, 1>
      <<<dim3(DOUT / 64, (M2 + 63) / 64), 256, 0, stream>>>(xn2, projd_w, projd_b, out, M2, DOUT, 192);
}

// Round 4
// 1639.757 us; speedup vs baseline: 1.5786x; 1.5786x over previous
//
#include <hip/hip_runtime.h>
#include <hip/hip_bf16.h>
#include <type_traits>

// ---------------- fixed problem dims ----------------
#define BB   16
#define N0   6273      // 1 + 8*28*28
#define NQ   1569      // 1 + 8*14*14
#define C3   576
#define HID  768
#define DOUT 384
#define M1   (BB*N0)   // 100368
#define M2   (BB*NQ)   // 25104

typedef __attribute__((ext_vector_type(8))) short  s16x8;
typedef __attribute__((ext_vector_type(8))) __bf16 bf16x8;
typedef __attribute__((ext_vector_type(4))) float  f32x4;

static __device__ __forceinline__ float bf2f(unsigned short u) {
  return __uint_as_float(((unsigned)u) << 16);
}
static __device__ __forceinline__ unsigned short f2bf(float f) {
  unsigned x = __float_as_uint(f);
  x += 0x7fffu + ((x >> 16) & 1u);   // RNE
  return (unsigned short)(x >> 16);
}
static __device__ __forceinline__ unsigned pk2(float a, float b) {
  return (unsigned)f2bf(a) | ((unsigned)f2bf(b) << 16);
}

// ---------------- LayerNorm over D=192, one wave per row ----------------
__global__ __launch_bounds__(256) void ln_rows_kernel(
    const float* __restrict__ in, const float* __restrict__ g,
    const float* __restrict__ bta, float* __restrict__ out, int rows) {
  int row = blockIdx.x * 4 + (threadIdx.x >> 6);
  int lane = threadIdx.x & 63;
  if (row >= rows) return;                 // whole wave exits together
  const float* p = in + (size_t)row * 192;
  float v0 = p[lane], v1 = p[lane + 64], v2 = p[lane + 128];
  float s = v0 + v1 + v2;
  float q = v0 * v0 + v1 * v1 + v2 * v2;
  #pragma unroll
  for (int m = 32; m; m >>= 1) { s += __shfl_xor(s, m, 64); q += __shfl_xor(q, m, 64); }
  float mean = s * (1.f / 192.f);
  float var  = q * (1.f / 192.f) - mean * mean;
  float rstd = rsqrtf(var + 1e-5f);
  float* po = out + (size_t)row * 192;
  po[lane]       = (v0 - mean) * rstd * g[lane]       + bta[lane];
  po[lane + 64]  = (v1 - mean) * rstd * g[lane + 64]  + bta[lane + 64];
  po[lane + 128] = (v2 - mean) * rstd * g[lane + 128] + bta[lane + 128];
}

// ---------------- generic tiled GEMM: C[M,N] = act(A[M,K]@B[K,N] + bias) (+C) ----
template <typename TA, typename TC, int ACT, int BETA>
__global__ __launch_bounds__(256) void gemm_kernel(
    const TA* __restrict__ A, const float* __restrict__ Bw,
    const float* __restrict__ bias, TC* __restrict__ C,
    int M, int Nn, int K) {
  __shared__ float As[16][68];
  __shared__ float Bs[16][68];
  const int tid = threadIdx.x;
  const int bm = blockIdx.y * 64;
  const int bn = blockIdx.x * 64;
  const int ty = tid >> 4, tx = tid & 15;
  const int r0 = ty * 4, c0 = tx * 4;
  const int la_m = tid >> 2;
  const int la_k = (tid & 3) * 4;
  const int lb_k = tid >> 4;
  const int lb_n = (tid & 15) * 4;
  float acc[4][4] = {};
  for (int k0 = 0; k0 < K; k0 += 16) {
    float4 av;
    int m = bm + la_m;
    if (m < M) {
      if constexpr (std::is_same<TA, float>::value) {
        av = *reinterpret_cast<const float4*>(A + (size_t)m * K + k0 + la_k);
      } else {
        ushort4 u = *reinterpret_cast<const ushort4*>(
            reinterpret_cast<const unsigned short*>(A) + (size_t)m * K + k0 + la_k);
        av = make_float4(bf2f(u.x), bf2f(u.y), bf2f(u.z), bf2f(u.w));
      }
    } else {
      av = make_float4(0.f, 0.f, 0.f, 0.f);
    }
    float4 bv = *reinterpret_cast<const float4*>(Bw + (size_t)(k0 + lb_k) * Nn + bn + lb_n);
    As[la_k + 0][la_m] = av.x;
    As[la_k + 1][la_m] = av.y;
    As[la_k + 2][la_m] = av.z;
    As[la_k + 3][la_m] = av.w;
    *reinterpret_cast<float4*>(&Bs[lb_k][lb_n]) = bv;
    __syncthreads();
    #pragma unroll
    for (int kk = 0; kk < 16; ++kk) {
      float4 a = *reinterpret_cast<const float4*>(&As[kk][r0]);
      float4 b = *reinterpret_cast<const float4*>(&Bs[kk][c0]);
      float ar[4] = {a.x, a.y, a.z, a.w};
      float br[4] = {b.x, b.y, b.z, b.w};
      #pragma unroll
      for (int i = 0; i < 4; ++i)
        #pragma unroll
        for (int j = 0; j < 4; ++j) acc[i][j] = fmaf(ar[i], br[j], acc[i][j]);
    }
    __syncthreads();
  }
  float bs[4];
  #pragma unroll
  for (int j = 0; j < 4; ++j) bs[j] = bias[bn + c0 + j];
  #pragma unroll
  for (int i = 0; i < 4; ++i) {
    int m = bm + r0 + i;
    if (m >= M) continue;
    #pragma unroll
    for (int j = 0; j < 4; ++j) {
      float v = acc[i][j] + bs[j];
      if (ACT == 1) v = 0.5f * v * (1.f + erff(v * 0.70710678118654752f));
      size_t oi = (size_t)m * Nn + bn + c0 + j;
      if (BETA) {
        if constexpr (std::is_same<TC, float>::value) v += C[oi];
        else v += bf2f(((const unsigned short*)C)[oi]);
      }
      if constexpr (std::is_same<TC, float>::value) C[oi] = v;
      else ((unsigned short*)C)[oi] = f2bf(v);
    }
  }
}

// ---------------- depthwise conv3d (3x3x3, stride 1,2,2, pad 1) + LN over hd=96 ---
// outputs bf16, optionally pre-scaled (softmax scale folded into Q)
__global__ __launch_bounds__(128) void pool_ln_kernel(
    const unsigned short* __restrict__ qkv, const float* __restrict__ w,
    const float* __restrict__ g, const float* __restrict__ bb,
    unsigned short* __restrict__ outp, int cidx, float oscale) {
  const int bid = blockIdx.x;
  const int l  = bid % NQ;
  const int bh = bid / NQ;
  const int h  = bh & 1;
  const int b  = bh >> 1;
  const int d  = threadIdx.x;
  __shared__ float red[128];
  __shared__ float stats[2];
  float val = 0.f;
  if (d < 96) {
    const unsigned short* base = qkv + (size_t)b * N0 * C3 + cidx * 192 + h * 96 + d;
    if (l == 0) {
      val = bf2f(base[0]);                          // cls token (n = 0)
    } else {
      int lp = l - 1;
      int to = lp / 196;
      int rem = lp - to * 196;
      int ho = rem / 14;
      int wo = rem - ho * 14;
      const float* wd = w + d * 27;
      #pragma unroll
      for (int kt = 0; kt < 3; ++kt) {
        int it = to + kt - 1;
        if ((unsigned)it >= 8u) continue;
        #pragma unroll
        for (int kh = 0; kh < 3; ++kh) {
          int ih = 2 * ho + kh - 1;
          if ((unsigned)ih >= 28u) continue;
          #pragma unroll
          for (int kw = 0; kw < 3; ++kw) {
            int iw = 2 * wo + kw - 1;
            if ((unsigned)iw >= 28u) continue;
            int n = 1 + (it * 28 + ih) * 28 + iw;
            val += wd[(kt * 3 + kh) * 3 + kw] * bf2f(base[(size_t)n * C3]);
          }
        }
      }
    }
  }
  red[d] = (d < 96) ? val : 0.f;
  __syncthreads();
  for (int s = 64; s > 0; s >>= 1) { if (d < s) red[d] += red[d + s]; __syncthreads(); }
  if (d == 0) stats[0] = red[0] * (1.f / 96.f);
  __syncthreads();
  float mean = stats[0];
  float dv = (d < 96) ? (val - mean) : 0.f;
  red[d] = dv * dv;
  __syncthreads();
  for (int s = 64; s > 0; s >>= 1) { if (d < s) red[d] += red[d + s]; __syncthreads(); }
  if (d == 0) stats[1] = rsqrtf(red[0] * (1.f / 96.f) + 1e-5f);
  __syncthreads();
  if (d < 96)
    outp[((size_t)bh * NQ + l) * 96 + d] =
        f2bf(((val - mean) * stats[1] * g[d] + bb[d]) * oscale);
}

// ---------------- MFMA flash attention (bf16, 16x16x32 only) --------------------
// Per block: 4 waves x 16 q-rows = 64 queries. KC=32 keys/chunk.
// Swapped QK^T: S^T = mfma(K, Q)  -> lane holds scores for q = lane&15.
// Swapped PV:   O^T = mfma(V^T, P^T) -> softmax state & rescale lane-local.
// Verified layouts: A row=l&15,k=8hi+j | B col=l&15,k=8hi+j | C/D col=l&15,row=4hi+r.
__global__ __launch_bounds__(256) void attn_mfma_kernel(
    const unsigned short* __restrict__ qb, const unsigned short* __restrict__ kb,
    const unsigned short* __restrict__ vb, float* __restrict__ o) {
  __shared__ alignas(16) unsigned short Ks[32][104];   // [key][d], stride 104 bf16 (208B)
  __shared__ alignas(16) unsigned short Vt[96 * 32];   // [d][key] XOR-swizzled, 6144B
  const int tid  = threadIdx.x;
  const int lane = tid & 63;
  const int wid  = tid >> 6;
  const int lo = lane & 15, hi = lane >> 4;
  const int bh = blockIdx.y;
  const int b = bh >> 1, h = bh & 1;
  const int q0 = blockIdx.x * 64 + wid * 16;
  const int qg = q0 + lo;

  const unsigned short* qbase = qb + (size_t)bh * NQ * 96;
  const unsigned short* kbase = kb + (size_t)bh * NQ * 96;
  const unsigned short* vbase = vb + (size_t)bh * NQ * 96;
  char* vtb = (char*)Vt;

  // Q fragments (B-operand), kept in registers for the whole kernel.
  s16x8 qf[3];
  if (qg < NQ) {
    const unsigned short* qrow = qbase + (size_t)qg * 96 + hi * 8;
    qf[0] = *(const s16x8*)(qrow);
    qf[1] = *(const s16x8*)(qrow + 32);
    qf[2] = *(const s16x8*)(qrow + 64);
  } else {
    #pragma unroll
    for (int j = 0; j < 8; ++j) { qf[0][j] = 0; qf[1][j] = 0; qf[2][j] = 0; }
  }

  f32x4 ot[6];
  #pragma unroll
  for (int t = 0; t < 6; ++t) { ot[t][0] = 0.f; ot[t][1] = 0.f; ot[t][2] = 0.f; ot[t][3] = 0.f; }
  float m = -1e30f, lsum = 0.f;

  for (int c = 0; c < (NQ + 31) / 32; ++c) {
    const int k0 = c * 32;
    // ---- stage K [32][96] bf16 (coalesced uint loads) ----
    #pragma unroll
    for (int j = 0; j < 6; ++j) {
      int u = tid + 256 * j;           // 0..1535 uints
      int kr = u / 48, c2 = u - kr * 48;
      unsigned val = 0;
      if (k0 + kr < NQ)
        val = *(const unsigned*)(kbase + (size_t)(k0 + kr) * 96 + c2 * 2);
      *(unsigned*)(&Ks[kr][c2 * 2]) = val;
    }
    // ---- stage V transposed + XOR-swizzled: Vt[d][k], byte = (d*64+2k)^((d&7)<<4) ----
    #pragma unroll
    for (int j = 0; j < 6; ++j) {
      int u = tid + 256 * j;
      int kr = u / 48, c2 = u - kr * 48;
      unsigned val = 0;
      if (k0 + kr < NQ)
        val = *(const unsigned*)(vbase + (size_t)(k0 + kr) * 96 + c2 * 2);
      int d0 = c2 * 2, d1 = d0 + 1;
      int o0 = (d0 * 64 + kr * 2) ^ ((d0 & 7) << 4);
      int o1 = (d1 * 64 + kr * 2) ^ ((d1 & 7) << 4);
      *(unsigned short*)(vtb + o0) = (unsigned short)(val & 0xffffu);
      *(unsigned short*)(vtb + o1) = (unsigned short)(val >> 16);
    }
    __syncthreads();
    // ---- S^T = K · Q^T  (keys 0-15 in st0, 16-31 in st1) ----
    f32x4 st0, st1;
    st0[0]=st0[1]=st0[2]=st0[3]=0.f;
    st1[0]=st1[1]=st1[2]=st1[3]=0.f;
    #pragma unroll
    for (int cc = 0; cc < 3; ++cc) {
      s16x8 kf0 = *(const s16x8*)(&Ks[lo][cc * 32 + hi * 8]);
      s16x8 kf1 = *(const s16x8*)(&Ks[16 + lo][cc * 32 + hi * 8]);
      st0 = __builtin_amdgcn_mfma_f32_16x16x32_bf16((bf16x8)kf0, (bf16x8)qf[cc], st0, 0, 0, 0);
      st1 = __builtin_amdgcn_mfma_f32_16x16x32_bf16((bf16x8)kf1, (bf16x8)qf[cc], st1, 0, 0, 0);
    }
    if (k0 + 32 > NQ) {   // mask OOB keys (last chunk only)
      #pragma unroll
      for (int r = 0; r < 4; ++r) {
        if (k0 + 4 * hi + r      >= NQ) st0[r] = -1e30f;
        if (k0 + 16 + 4 * hi + r >= NQ) st1[r] = -1e30f;
      }
    }
    // ---- online softmax (q = lo; partner lanes differ in bits 4,5) ----
    float mc = fmaxf(fmaxf(fmaxf(st0[0], st0[1]), fmaxf(st0[2], st0[3])),
                     fmaxf(fmaxf(st1[0], st1[1]), fmaxf(st1[2], st1[3])));
    mc = fmaxf(mc, __shfl_xor(mc, 16));
    mc = fmaxf(mc, __shfl_xor(mc, 32));
    if (!__all(mc <= m)) {           // defer-max: skip rescale when max didn't grow
      float mnew = fmaxf(m, mc);
      float alpha = __expf(m - mnew);
      #pragma unroll
      for (int t = 0; t < 6; ++t) {
        ot[t][0] *= alpha; ot[t][1] *= alpha; ot[t][2] *= alpha; ot[t][3] *= alpha;
      }
      lsum *= alpha;
      m = mnew;
    }
    float p0[4], p1[4], sum = 0.f;
    #pragma unroll
    for (int r = 0; r < 4; ++r) {
      p0[r] = __expf(st0[r] - m);
      p1[r] = __expf(st1[r] - m);
      sum += p0[r] + p1[r];
    }
    sum += __shfl_xor(sum, 16);
    sum += __shfl_xor(sum, 32);
    lsum += sum;
    // ---- redistribute P: C/D key order (4hi+r) -> B-frag key order (8hi+j) ----
    unsigned w00 = pk2(p0[0], p0[1]), w01 = pk2(p0[2], p0[3]);
    unsigned w10 = pk2(p1[0], p1[1]), w11 = pk2(p1[2], p1[3]);
    unsigned w00x = __shfl_xor(w00, 32), w01x = __shfl_xor(w01, 32);
    unsigned w10x = __shfl_xor(w10, 32), w11x = __shfl_xor(w11, 32);
    unsigned w00y = __shfl_xor(w00, 16), w01y = __shfl_xor(w01, 16);
    unsigned w10y = __shfl_xor(w10, 16), w11y = __shfl_xor(w11, 16);
    unsigned w00z = __shfl_xor(w00x, 16), w01z = __shfl_xor(w01x, 16);
    unsigned w10z = __shfl_xor(w10x, 16), w11z = __shfl_xor(w11x, 16);
    bool h0 = (hi == 0), h1 = (hi == 1), h2 = (hi == 2);
    union { unsigned u[4]; s16x8 v; } pf;
    pf.u[0] = h0 ? w00  : h1 ? w00z : h2 ? w10x : w10y;
    pf.u[1] = h0 ? w01  : h1 ? w01z : h2 ? w11x : w11y;
    pf.u[2] = h0 ? w00y : h1 ? w00x : h2 ? w10z : w10;
    pf.u[3] = h0 ? w01y : h1 ? w01x : h2 ? w11z : w11;
    // ---- O^T += V^T · P^T  (6 d-tiles of 16) ----
    #pragma unroll
    for (int t = 0; t < 6; ++t) {
      int d = 16 * t + lo;
      int off = (d * 64 + hi * 16) ^ ((d & 7) << 4);
      s16x8 va = *(const s16x8*)(vtb + off);
      ot[t] = __builtin_amdgcn_mfma_f32_16x16x32_bf16((bf16x8)va, (bf16x8)pf.v, ot[t], 0, 0, 0);
    }
    __syncthreads();
  }
  // ---- store O (normalize; lane q = lo, d = 16t + 4hi + r) ----
  if (qg < NQ) {
    float invl = 1.f / lsum;
    float* po = o + ((size_t)b * NQ + qg) * 192 + h * 96 + hi * 4;
    #pragma unroll
    for (int t = 0; t < 6; ++t) {
      float4 v4 = make_float4(ot[t][0] * invl, ot[t][1] * invl,
                              ot[t][2] * invl, ot[t][3] * invl);
      *(float4*)(po + 16 * t) = v4;
    }
  }
}

// ---------------- maxpool (1,3,3)/(1,2,2)/pad(0,1,1) skip path -> x1 -------------
__global__ __launch_bounds__(256) void maxpool_kernel(
    const float* __restrict__ x, float* __restrict__ x1) {
  int idx = blockIdx.x * 256 + threadIdx.x;
  const int total = BB * NQ * 192;
  if (idx >= total) return;
  int cc = idx % 192;
  int rem = idx / 192;
  int l = rem % NQ;
  int b = rem / NQ;
  const float* xb = x + (size_t)b * N0 * 192;
  float m;
  if (l == 0) {
    m = xb[cc];
  } else {
    int lp = l - 1;
    int to = lp / 196;
    int r2 = lp - to * 196;
    int ho = r2 / 14;
    int wo = r2 - ho * 14;
    m = -INFINITY;
    #pragma unroll
    for (int kh = 0; kh < 3; ++kh) {
      int ih = 2 * ho + kh - 1;
      if ((unsigned)ih >= 28u) continue;
      #pragma unroll
      for (int kw = 0; kw < 3; ++kw) {
        int iw = 2 * wo + kw - 1;
        if ((unsigned)iw >= 28u) continue;
        int n = 1 + (to * 28 + ih) * 28 + iw;
        m = fmaxf(m, xb[(size_t)n * 192 + cc]);
      }
    }
  }
  x1[idx] = m;
}

// ---------------- launch ----------------
extern "C" void kernel_launch(void* const* d_in, const int* in_sizes, int n_in,
                              void* d_out, int out_size, void* d_ws, size_t ws_size,
                              hipStream_t stream) {
  (void)in_sizes; (void)n_in; (void)out_size; (void)ws_size;
  const float* x       = (const float*)d_in[0];
  const float* ln1_g   = (const float*)d_in[1];
  const float* ln1_b   = (const float*)d_in[2];
  const float* qkv_w   = (const float*)d_in[3];
  const float* qkv_b   = (const float*)d_in[4];
  const float* pq_w    = (const float*)d_in[5];
  const float* pk_w    = (const float*)d_in[6];
  const float* pv_w    = (const float*)d_in[7];
  const float* nq_g    = (const float*)d_in[8];
  const float* nq_b    = (const float*)d_in[9];
  const float* nk_g    = (const float*)d_in[10];
  const float* nk_b    = (const float*)d_in[11];
  const float* nv_g    = (const float*)d_in[12];
  const float* nv_b    = (const float*)d_in[13];
  const float* proj_w  = (const float*)d_in[14];
  const float* proj_b  = (const float*)d_in[15];
  const float* ln2_g   = (const float*)d_in[16];
  const float* ln2_b   = (const float*)d_in[17];
  const float* fc1_w   = (const float*)d_in[18];
  const float* fc1_b   = (const float*)d_in[19];
  const float* fc2_w   = (const float*)d_in[20];
  const float* fc2_b   = (const float*)d_in[21];
  const float* projd_w = (const float*)d_in[22];
  const float* projd_b = (const float*)d_in[23];

  // workspace layout (bytes); total 192,706,560 B (~184 MB), same as round 0.
  char* ws = (char*)d_ws;
  float* xn            = (float*)(ws);                       // 77,082,624 B
  unsigned short* qkvb = (unsigned short*)(ws + 77082624);   // 115,623,936 B
  // region-1 reuse (xn dead after qkv GEMM): bf16 pooled q/k/v, 9,639,936 B each
  unsigned short* qbuf = (unsigned short*)(ws);
  unsigned short* kbuf = (unsigned short*)(ws + 9639936);
  unsigned short* vbuf = (unsigned short*)(ws + 19279872);
  // region-2 reuse (qkv dead after pooling):
  char* r2 = ws + 77082624;
  float* ob            = (float*)(r2);
  float* x1            = (float*)(r2 + 19279872);
  float* xn2           = (float*)(r2 + 38559744);
  unsigned short* hmid = (unsigned short*)(r2 + 57839616);
  float* out = (float*)d_out;

  const float scale = 0.10206207261596577f;  // 1/sqrt(96), folded into Q

  // 1) xn = LN(x)
  ln_rows_kernel<<<(M1 + 3) / 4, 256, 0, stream>>>(x, ln1_g, ln1_b, xn, M1);
  // 2) qkv = xn @ qkv_w + qkv_b   (stored bf16)
  gemm_kernel<float, unsigned short, 0, 0>
      <<<dim3(C3 / 64, (M1 + 63) / 64), 256, 0, stream>>>(xn, qkv_w, qkv_b, qkvb, M1, C3, 192);
  // 3) pooled+LN q, k, v  (bf16 out; q pre-scaled)
  pool_ln_kernel<<<BB * 2 * NQ, 128, 0, stream>>>(qkvb, pq_w, nq_g, nq_b, qbuf, 0, scale);
  pool_ln_kernel<<<BB * 2 * NQ, 128, 0, stream>>>(qkvb, pk_w, nk_g, nk_b, kbuf, 1, 1.f);
  pool_ln_kernel<<<BB * 2 * NQ, 128, 0, stream>>>(qkvb, pv_w, nv_g, nv_b, vbuf, 2, 1.f);
  // 4) o = softmax(qk^T) v  (MFMA flash)  -> [B, NQ, 192]
  attn_mfma_kernel<<<dim3((NQ + 63) / 64, BB * 2), 256, 0, stream>>>(qbuf, kbuf, vbuf, ob);
  // 5) x1 = maxpool_skip(x)
  maxpool_kernel<<<(BB * NQ * 192 + 255) / 256, 256, 0, stream>>>(x, x1);
  // 6) x1 += o @ proj_w + proj_b
  gemm_kernel<float, float, 0, 1>
      <<<dim3(192 / 64, (M2 + 63) / 64), 256, 0, stream>>>(ob, proj_w, proj_b, x1, M2, 192, 192);
  // 7) xn2 = LN(x1)
  ln_rows_kernel<<<(M2 + 3) / 4, 256, 0, stream>>>(x1, ln2_g, ln2_b, xn2, M2);
  // 8) hmid = gelu(xn2 @ fc1_w + fc1_b)   (stored bf16)
  gemm_kernel<float, unsigned short, 1, 0>
      <<<dim3(HID / 64, (M2 + 63) / 64), 256, 0, stream>>>(xn2, fc1_w, fc1_b, hmid, M2, HID, 192);
  // 9) out = hmid @ fc2_w + fc2_b
  gemm_kernel<unsigned short, float, 0, 0>
      <<<dim3(DOUT / 64, (M2 + 63) / 64), 256, 0, stream>>>(hmid, fc2_w, fc2_b, out, M2, DOUT, HID);
  // 10) out += xn2 @ projd_w + projd_b
  gemm_kernel<float, float, 0, 1>
      <<<dim3(DOUT / 64, (M2 + 63) / 64), 256, 0, stream>>>(xn2, projd_w, projd_b, out, M2, DOUT, 192);
}

// Round 9
// 1344.203 us; speedup vs baseline: 1.9257x; 1.2199x over previous
//
#include <hip/hip_runtime.h>
#include <hip/hip_bf16.h>
#include <type_traits>

// ---------------- fixed problem dims ----------------
#define BB   16
#define N0   6273      // 1 + 8*28*28
#define NQ   1569      // 1 + 8*14*14
#define C3   576
#define HID  768
#define DOUT 384
#define M1   (BB*N0)   // 100368
#define M2   (BB*NQ)   // 25104

typedef __attribute__((ext_vector_type(8))) short  s16x8;
typedef __attribute__((ext_vector_type(8))) __bf16 bf16x8;
typedef __attribute__((ext_vector_type(4))) float  f32x4;

static __device__ __forceinline__ float bf2f(unsigned short u) {
  return __uint_as_float(((unsigned)u) << 16);
}
static __device__ __forceinline__ unsigned short f2bf(float f) {
  unsigned x = __float_as_uint(f);
  x += 0x7fffu + ((x >> 16) & 1u);   // RNE
  return (unsigned short)(x >> 16);
}
static __device__ __forceinline__ unsigned pk2(float a, float b) {
  return (unsigned)f2bf(a) | ((unsigned)f2bf(b) << 16);
}

// ---------------- LayerNorm over D=192 -> bf16 out (ldc stride) ----------------
__global__ __launch_bounds__(256) void ln_rows_bf16_kernel(
    const float* __restrict__ in, const float* __restrict__ g,
    const float* __restrict__ bta, unsigned short* __restrict__ out,
    int rows, int ldc) {
  int row = blockIdx.x * 4 + (threadIdx.x >> 6);
  int lane = threadIdx.x & 63;
  if (row >= rows) return;                 // whole wave exits together
  const float* p = in + (size_t)row * 192;
  float v0 = p[lane], v1 = p[lane + 64], v2 = p[lane + 128];
  float s = v0 + v1 + v2;
  float q = v0 * v0 + v1 * v1 + v2 * v2;
  #pragma unroll
  for (int m = 32; m; m >>= 1) { s += __shfl_xor(s, m, 64); q += __shfl_xor(q, m, 64); }
  float mean = s * (1.f / 192.f);
  float var  = q * (1.f / 192.f) - mean * mean;
  float rstd = rsqrtf(var + 1e-5f);
  unsigned short* po = out + (size_t)row * ldc;
  po[lane]       = f2bf((v0 - mean) * rstd * g[lane]       + bta[lane]);
  po[lane + 64]  = f2bf((v1 - mean) * rstd * g[lane + 64]  + bta[lane + 64]);
  po[lane + 128] = f2bf((v2 - mean) * rstd * g[lane + 128] + bta[lane + 128]);
}

// ---------------- weight prep: fp32 [K][N] -> bf16 [N][K] ----------------
__global__ __launch_bounds__(256) void wtrans_kernel(
    const float* __restrict__ in, unsigned short* __restrict__ out, int K, int N) {
  int idx = blockIdx.x * 256 + threadIdx.x;
  if (idx >= K * N) return;
  int n = idx / K, k = idx - n * K;
  out[idx] = f2bf(in[k * N + n]);
}

// combined [fc2_w; projd_w] -> bf16 [384][960], bias sum -> bc[384]
__global__ __launch_bounds__(256) void wcomb_kernel(
    const float* __restrict__ fc2w, const float* __restrict__ projdw,
    const float* __restrict__ fc2b, const float* __restrict__ projdb,
    unsigned short* __restrict__ wT, float* __restrict__ bc) {
  int idx = blockIdx.x * 256 + threadIdx.x;
  if (idx < 384 * 960) {
    int n = idx / 960, k = idx - n * 960;
    float v = (k < 768) ? fc2w[k * 384 + n] : projdw[(k - 768) * 384 + n];
    wT[idx] = f2bf(v);
  }
  if (idx < 384) bc[idx] = fc2b[idx] + projdb[idx];
}

// ---------------- MFMA GEMM: C[M][N] = act(A[M][K]bf16 @ BT[N][K]^T + bias) (+C)
// BM=128 BN=64 BK=64, 256 thr / 4 waves, wave tile 32(m) x 64(n).
// LDS XOR swizzle: byte(row, cb) = row*128 + ((cb ^ (row&7)) << 4), cb in 0..7.
template <int ACT, int BETA, typename TC>
__global__ __launch_bounds__(256) void gemm_mfma_kernel(
    const unsigned short* __restrict__ A, const unsigned short* __restrict__ BT,
    const float* __restrict__ bias, TC* __restrict__ C,
    int M, int N, int K, int lda, int ldc) {
  __shared__ alignas(16) unsigned short As[128 * 64];   // 16 KB
  __shared__ alignas(16) unsigned short Bs[64 * 64];    //  8 KB
  const int tid = threadIdx.x;
  const int lane = tid & 63, wid = tid >> 6;
  const int lo = lane & 15, hi = lane >> 4;
  const int bm = blockIdx.y * 128;
  const int bn = blockIdx.x * 64;
  const int s_row = tid >> 3;        // 0..31
  const int s_cb  = tid & 7;         // 0..7
  const int wrow  = wid * 32;
  char* asb = (char*)As;
  char* bsb = (char*)Bs;
  f32x4 acc[2][4];
  #pragma unroll
  for (int mi = 0; mi < 2; ++mi)
    #pragma unroll
    for (int nj = 0; nj < 4; ++nj) {
      acc[mi][nj][0] = 0.f; acc[mi][nj][1] = 0.f;
      acc[mi][nj][2] = 0.f; acc[mi][nj][3] = 0.f;
    }
  for (int k0 = 0; k0 < K; k0 += 64) {
    uint4 av[4], bv[2];
    #pragma unroll
    for (int i = 0; i < 4; ++i) {
      int row = s_row + 32 * i;
      int rg = bm + row; if (rg > M - 1) rg = M - 1;
      av[i] = *(const uint4*)(A + (size_t)rg * lda + k0 + s_cb * 8);
    }
    #pragma unroll
    for (int i = 0; i < 2; ++i) {
      int col = s_row + 32 * i;
      bv[i] = *(const uint4*)(BT + (size_t)(bn + col) * K + k0 + s_cb * 8);
    }
    if (k0) __syncthreads();           // prev compute done before overwrite
    #pragma unroll
    for (int i = 0; i < 4; ++i) {
      int row = s_row + 32 * i;
      *(uint4*)(asb + row * 128 + ((s_cb ^ (row & 7)) << 4)) = av[i];
    }
    #pragma unroll
    for (int i = 0; i < 2; ++i) {
      int col = s_row + 32 * i;
      *(uint4*)(bsb + col * 128 + ((s_cb ^ (col & 7)) << 4)) = bv[i];
    }
    __syncthreads();
    #pragma unroll
    for (int ks = 0; ks < 2; ++ks) {
      s16x8 af[2], bf[4];
      #pragma unroll
      for (int mi = 0; mi < 2; ++mi) {
        int row = wrow + mi * 16 + lo;
        af[mi] = *(const s16x8*)(asb + row * 128 + (((ks * 4 + hi) ^ (row & 7)) << 4));
      }
      #pragma unroll
      for (int nj = 0; nj < 4; ++nj) {
        int col = nj * 16 + lo;
        bf[nj] = *(const s16x8*)(bsb + col * 128 + (((ks * 4 + hi) ^ (col & 7)) << 4));
      }
      #pragma unroll
      for (int mi = 0; mi < 2; ++mi)
        #pragma unroll
        for (int nj = 0; nj < 4; ++nj)
          acc[mi][nj] = __builtin_amdgcn_mfma_f32_16x16x32_bf16(
              (bf16x8)af[mi], (bf16x8)bf[nj], acc[mi][nj], 0, 0, 0);
    }
  }
  // epilogue: D col = lo, row = 4*hi + r
  #pragma unroll
  for (int nj = 0; nj < 4; ++nj) {
    float bsv = bias[bn + nj * 16 + lo];
    #pragma unroll
    for (int mi = 0; mi < 2; ++mi) {
      int rowb = bm + wrow + mi * 16 + hi * 4;
      #pragma unroll
      for (int r = 0; r < 4; ++r) {
        int row = rowb + r;
        if (row >= M) continue;
        float v = acc[mi][nj][r] + bsv;
        if (ACT == 1) v = 0.5f * v * (1.f + erff(v * 0.70710678118654752f));
        size_t oi = (size_t)row * ldc + bn + nj * 16 + lo;
        if constexpr (BETA != 0) {
          if constexpr (std::is_same<TC, float>::value) v += C[oi];
          else v += bf2f(C[oi]);
        }
        if constexpr (std::is_same<TC, float>::value) C[oi] = v;
        else C[oi] = f2bf(v);
      }
    }
  }
}

// ---------------- depthwise conv3d (3x3x3, stride 1,2,2, pad 1) + LN over hd=96 ---
__global__ __launch_bounds__(128) void pool_ln_kernel(
    const unsigned short* __restrict__ qkv, const float* __restrict__ w,
    const float* __restrict__ g, const float* __restrict__ bb,
    unsigned short* __restrict__ outp, int cidx, float oscale) {
  const int bid = blockIdx.x;
  const int l  = bid % NQ;
  const int bh = bid / NQ;
  const int h  = bh & 1;
  const int b  = bh >> 1;
  const int d  = threadIdx.x;
  __shared__ float red[128];
  __shared__ float stats[2];
  float val = 0.f;
  if (d < 96) {
    const unsigned short* base = qkv + (size_t)b * N0 * C3 + cidx * 192 + h * 96 + d;
    if (l == 0) {
      val = bf2f(base[0]);                          // cls token (n = 0)
    } else {
      int lp = l - 1;
      int to = lp / 196;
      int rem = lp - to * 196;
      int ho = rem / 14;
      int wo = rem - ho * 14;
      const float* wd = w + d * 27;
      #pragma unroll
      for (int kt = 0; kt < 3; ++kt) {
        int it = to + kt - 1;
        if ((unsigned)it >= 8u) continue;
        #pragma unroll
        for (int kh = 0; kh < 3; ++kh) {
          int ih = 2 * ho + kh - 1;
          if ((unsigned)ih >= 28u) continue;
          #pragma unroll
          for (int kw = 0; kw < 3; ++kw) {
            int iw = 2 * wo + kw - 1;
            if ((unsigned)iw >= 28u) continue;
            int n = 1 + (it * 28 + ih) * 28 + iw;
            val += wd[(kt * 3 + kh) * 3 + kw] * bf2f(base[(size_t)n * C3]);
          }
        }
      }
    }
  }
  red[d] = (d < 96) ? val : 0.f;
  __syncthreads();
  for (int s = 64; s > 0; s >>= 1) { if (d < s) red[d] += red[d + s]; __syncthreads(); }
  if (d == 0) stats[0] = red[0] * (1.f / 96.f);
  __syncthreads();
  float mean = stats[0];
  float dv = (d < 96) ? (val - mean) : 0.f;
  red[d] = dv * dv;
  __syncthreads();
  for (int s = 64; s > 0; s >>= 1) { if (d < s) red[d] += red[d + s]; __syncthreads(); }
  if (d == 0) stats[1] = rsqrtf(red[0] * (1.f / 96.f) + 1e-5f);
  __syncthreads();
  if (d < 96)
    outp[((size_t)bh * NQ + l) * 96 + d] =
        f2bf(((val - mean) * stats[1] * g[d] + bb[d]) * oscale);
}

// ---------------- MFMA flash attention (bf16, 16x16x32), bf16 out ---------------
__global__ __launch_bounds__(256) void attn_mfma_kernel(
    const unsigned short* __restrict__ qb, const unsigned short* __restrict__ kb,
    const unsigned short* __restrict__ vb, unsigned short* __restrict__ o) {
  __shared__ alignas(16) unsigned short Ks[32][104];   // [key][d]
  __shared__ alignas(16) unsigned short Vt[96 * 32];   // [d][key] XOR-swizzled
  const int tid  = threadIdx.x;
  const int lane = tid & 63;
  const int wid  = tid >> 6;
  const int lo = lane & 15, hi = lane >> 4;
  const int bh = blockIdx.y;
  const int b = bh >> 1, h = bh & 1;
  const int q0 = blockIdx.x * 64 + wid * 16;
  const int qg = q0 + lo;

  const unsigned short* qbase = qb + (size_t)bh * NQ * 96;
  const unsigned short* kbase = kb + (size_t)bh * NQ * 96;
  const unsigned short* vbase = vb + (size_t)bh * NQ * 96;
  char* vtb = (char*)Vt;

  s16x8 qf[3];
  if (qg < NQ) {
    const unsigned short* qrow = qbase + (size_t)qg * 96 + hi * 8;
    qf[0] = *(const s16x8*)(qrow);
    qf[1] = *(const s16x8*)(qrow + 32);
    qf[2] = *(const s16x8*)(qrow + 64);
  } else {
    #pragma unroll
    for (int j = 0; j < 8; ++j) { qf[0][j] = 0; qf[1][j] = 0; qf[2][j] = 0; }
  }

  f32x4 ot[6];
  #pragma unroll
  for (int t = 0; t < 6; ++t) { ot[t][0] = 0.f; ot[t][1] = 0.f; ot[t][2] = 0.f; ot[t][3] = 0.f; }
  float m = -1e30f, lsum = 0.f;

  for (int c = 0; c < (NQ + 31) / 32; ++c) {
    const int k0 = c * 32;
    #pragma unroll
    for (int j = 0; j < 6; ++j) {
      int u = tid + 256 * j;
      int kr = u / 48, c2 = u - kr * 48;
      unsigned val = 0;
      if (k0 + kr < NQ)
        val = *(const unsigned*)(kbase + (size_t)(k0 + kr) * 96 + c2 * 2);
      *(unsigned*)(&Ks[kr][c2 * 2]) = val;
    }
    #pragma unroll
    for (int j = 0; j < 6; ++j) {
      int u = tid + 256 * j;
      int kr = u / 48, c2 = u - kr * 48;
      unsigned val = 0;
      if (k0 + kr < NQ)
        val = *(const unsigned*)(vbase + (size_t)(k0 + kr) * 96 + c2 * 2);
      int d0 = c2 * 2, d1 = d0 + 1;
      int o0 = (d0 * 64 + kr * 2) ^ ((d0 & 7) << 4);
      int o1 = (d1 * 64 + kr * 2) ^ ((d1 & 7) << 4);
      *(unsigned short*)(vtb + o0) = (unsigned short)(val & 0xffffu);
      *(unsigned short*)(vtb + o1) = (unsigned short)(val >> 16);
    }
    __syncthreads();
    f32x4 st0, st1;
    st0[0]=st0[1]=st0[2]=st0[3]=0.f;
    st1[0]=st1[1]=st1[2]=st1[3]=0.f;
    #pragma unroll
    for (int cc = 0; cc < 3; ++cc) {
      s16x8 kf0 = *(const s16x8*)(&Ks[lo][cc * 32 + hi * 8]);
      s16x8 kf1 = *(const s16x8*)(&Ks[16 + lo][cc * 32 + hi * 8]);
      st0 = __builtin_amdgcn_mfma_f32_16x16x32_bf16((bf16x8)kf0, (bf16x8)qf[cc], st0, 0, 0, 0);
      st1 = __builtin_amdgcn_mfma_f32_16x16x32_bf16((bf16x8)kf1, (bf16x8)qf[cc], st1, 0, 0, 0);
    }
    if (k0 + 32 > NQ) {
      #pragma unroll
      for (int r = 0; r < 4; ++r) {
        if (k0 + 4 * hi + r      >= NQ) st0[r] = -1e30f;
        if (k0 + 16 + 4 * hi + r >= NQ) st1[r] = -1e30f;
      }
    }
    float mc = fmaxf(fmaxf(fmaxf(st0[0], st0[1]), fmaxf(st0[2], st0[3])),
                     fmaxf(fmaxf(st1[0], st1[1]), fmaxf(st1[2], st1[3])));
    mc = fmaxf(mc, __shfl_xor(mc, 16));
    mc = fmaxf(mc, __shfl_xor(mc, 32));
    if (!__all(mc <= m)) {
      float mnew = fmaxf(m, mc);
      float alpha = __expf(m - mnew);
      #pragma unroll
      for (int t = 0; t < 6; ++t) {
        ot[t][0] *= alpha; ot[t][1] *= alpha; ot[t][2] *= alpha; ot[t][3] *= alpha;
      }
      lsum *= alpha;
      m = mnew;
    }
    float p0[4], p1[4], sum = 0.f;
    #pragma unroll
    for (int r = 0; r < 4; ++r) {
      p0[r] = __expf(st0[r] - m);
      p1[r] = __expf(st1[r] - m);
      sum += p0[r] + p1[r];
    }
    sum += __shfl_xor(sum, 16);
    sum += __shfl_xor(sum, 32);
    lsum += sum;
    unsigned w00 = pk2(p0[0], p0[1]), w01 = pk2(p0[2], p0[3]);
    unsigned w10 = pk2(p1[0], p1[1]), w11 = pk2(p1[2], p1[3]);
    unsigned w00x = __shfl_xor(w00, 32), w01x = __shfl_xor(w01, 32);
    unsigned w10x = __shfl_xor(w10, 32), w11x = __shfl_xor(w11, 32);
    unsigned w00y = __shfl_xor(w00, 16), w01y = __shfl_xor(w01, 16);
    unsigned w10y = __shfl_xor(w10, 16), w11y = __shfl_xor(w11, 16);
    unsigned w00z = __shfl_xor(w00x, 16), w01z = __shfl_xor(w01x, 16);
    unsigned w10z = __shfl_xor(w10x, 16), w11z = __shfl_xor(w11x, 16);
    bool h0 = (hi == 0), h1 = (hi == 1), h2 = (hi == 2);
    union { unsigned u[4]; s16x8 v; } pf;
    pf.u[0] = h0 ? w00  : h1 ? w00z : h2 ? w10x : w10y;
    pf.u[1] = h0 ? w01  : h1 ? w01z : h2 ? w11x : w11y;
    pf.u[2] = h0 ? w00y : h1 ? w00x : h2 ? w10z : w10;
    pf.u[3] = h0 ? w01y : h1 ? w01x : h2 ? w11z : w11;
    #pragma unroll
    for (int t = 0; t < 6; ++t) {
      int d = 16 * t + lo;
      int off = (d * 64 + hi * 16) ^ ((d & 7) << 4);
      s16x8 va = *(const s16x8*)(vtb + off);
      ot[t] = __builtin_amdgcn_mfma_f32_16x16x32_bf16((bf16x8)va, (bf16x8)pf.v, ot[t], 0, 0, 0);
    }
    __syncthreads();
  }
  if (qg < NQ) {
    float invl = 1.f / lsum;
    unsigned short* po = o + ((size_t)b * NQ + qg) * 192 + h * 96 + hi * 4;
    #pragma unroll
    for (int t = 0; t < 6; ++t) {
      ushort4 u4;
      u4.x = f2bf(ot[t][0] * invl); u4.y = f2bf(ot[t][1] * invl);
      u4.z = f2bf(ot[t][2] * invl); u4.w = f2bf(ot[t][3] * invl);
      *(ushort4*)(po + 16 * t) = u4;
    }
  }
}

// ---------------- maxpool (1,3,3)/(1,2,2)/pad(0,1,1) skip path -> x1 -------------
__global__ __launch_bounds__(256) void maxpool_kernel(
    const float* __restrict__ x, float* __restrict__ x1) {
  int idx = blockIdx.x * 256 + threadIdx.x;
  const int total = BB * NQ * 192;
  if (idx >= total) return;
  int cc = idx % 192;
  int rem = idx / 192;
  int l = rem % NQ;
  int b = rem / NQ;
  const float* xb = x + (size_t)b * N0 * 192;
  float m;
  if (l == 0) {
    m = xb[cc];
  } else {
    int lp = l - 1;
    int to = lp / 196;
    int r2 = lp - to * 196;
    int ho = r2 / 14;
    int wo = r2 - ho * 14;
    m = -INFINITY;
    #pragma unroll
    for (int kh = 0; kh < 3; ++kh) {
      int ih = 2 * ho + kh - 1;
      if ((unsigned)ih >= 28u) continue;
      #pragma unroll
      for (int kw = 0; kw < 3; ++kw) {
        int iw = 2 * wo + kw - 1;
        if ((unsigned)iw >= 28u) continue;
        int n = 1 + (to * 28 + ih) * 28 + iw;
        m = fmaxf(m, xb[(size_t)n * 192 + cc]);
      }
    }
  }
  x1[idx] = m;
}

// ---------------- launch ----------------
extern "C" void kernel_launch(void* const* d_in, const int* in_sizes, int n_in,
                              void* d_out, int out_size, void* d_ws, size_t ws_size,
                              hipStream_t stream) {
  (void)in_sizes; (void)n_in; (void)out_size; (void)ws_size;
  const float* x       = (const float*)d_in[0];
  const float* ln1_g   = (const float*)d_in[1];
  const float* ln1_b   = (const float*)d_in[2];
  const float* qkv_w   = (const float*)d_in[3];
  const float* qkv_b   = (const float*)d_in[4];
  const float* pq_w    = (const float*)d_in[5];
  const float* pk_w    = (const float*)d_in[6];
  const float* pv_w    = (const float*)d_in[7];
  const float* nq_g    = (const float*)d_in[8];
  const float* nq_b    = (const float*)d_in[9];
  const float* nk_g    = (const float*)d_in[10];
  const float* nk_b    = (const float*)d_in[11];
  const float* nv_g    = (const float*)d_in[12];
  const float* nv_b    = (const float*)d_in[13];
  const float* proj_w  = (const float*)d_in[14];
  const float* proj_b  = (const float*)d_in[15];
  const float* ln2_g   = (const float*)d_in[16];
  const float* ln2_b   = (const float*)d_in[17];
  const float* fc1_w   = (const float*)d_in[18];
  const float* fc1_b   = (const float*)d_in[19];
  const float* fc2_w   = (const float*)d_in[20];
  const float* fc2_b   = (const float*)d_in[21];
  const float* projd_w = (const float*)d_in[22];
  const float* projd_b = (const float*)d_in[23];

  // ---- workspace layout (bytes), total ~155.5 MB ----
  char* ws = (char*)d_ws;
  // region 1: xnb [M1][192] bf16 (38,541,312 B); reused for pooled q/k/v bf16
  unsigned short* xnb  = (unsigned short*)(ws);
  unsigned short* qbuf = (unsigned short*)(ws);
  unsigned short* kbuf = (unsigned short*)(ws + 9639936);
  unsigned short* vbuf = (unsigned short*)(ws + 19279872);
  // region 2: qkvb [M1][576] bf16 (115,623,936 B); reused after pooling:
  char* r2 = ws + 38541312;
  unsigned short* qkvb = (unsigned short*)(r2);
  unsigned short* obb  = (unsigned short*)(r2);               //  9,639,936 B
  float*          x1   = (float*)(r2 + 9639936);              // 19,279,872 B
  unsigned short* comb = (unsigned short*)(r2 + 28919808);    // 48,199,680 B [M2][960]
  // region 3: prepped weights (after 38,541,312 + 115,623,936 = 154,165,248)
  char* r3 = ws + 154165248;
  unsigned short* qkv_wT  = (unsigned short*)(r3);            // [576][192] 221,184 B
  unsigned short* proj_wT = (unsigned short*)(r3 + 221184);   // [192][192]  73,728 B
  unsigned short* fc1_wT  = (unsigned short*)(r3 + 294912);   // [768][192] 294,912 B
  unsigned short* wcombT  = (unsigned short*)(r3 + 589824);   // [384][960] 737,280 B
  float*          bcomb   = (float*)(r3 + 1327104);           //  1,536 B
  float* out = (float*)d_out;

  const float scale = 0.10206207261596577f;  // 1/sqrt(96), folded into Q

  // 0) weight prep
  wtrans_kernel<<<(576 * 192 + 255) / 256, 256, 0, stream>>>(qkv_w, qkv_wT, 192, 576);
  wtrans_kernel<<<(192 * 192 + 255) / 256, 256, 0, stream>>>(proj_w, proj_wT, 192, 192);
  wtrans_kernel<<<(768 * 192 + 255) / 256, 256, 0, stream>>>(fc1_w, fc1_wT, 192, 768);
  wcomb_kernel<<<(384 * 960 + 255) / 256, 256, 0, stream>>>(fc2_w, projd_w, fc2_b, projd_b,
                                                            wcombT, bcomb);
  // 1) xnb = LN(x)  (bf16)
  ln_rows_bf16_kernel<<<(M1 + 3) / 4, 256, 0, stream>>>(x, ln1_g, ln1_b, xnb, M1, 192);
  // 2) qkv = xnb @ qkv_w + qkv_b  (bf16)
  gemm_mfma_kernel<0, 0, unsigned short>
      <<<dim3(C3 / 64, (M1 + 127) / 128), 256, 0, stream>>>(
          xnb, qkv_wT, qkv_b, qkvb, M1, C3, 192, 192, C3);
  // 3) pooled+LN q, k, v  (bf16; q pre-scaled)
  pool_ln_kernel<<<BB * 2 * NQ, 128, 0, stream>>>(qkvb, pq_w, nq_g, nq_b, qbuf, 0, scale);
  pool_ln_kernel<<<BB * 2 * NQ, 128, 0, stream>>>(qkvb, pk_w, nk_g, nk_b, kbuf, 1, 1.f);
  pool_ln_kernel<<<BB * 2 * NQ, 128, 0, stream>>>(qkvb, pv_w, nv_g, nv_b, vbuf, 2, 1.f);
  // 4) o = softmax(qk^T) v  (MFMA flash) -> bf16 [B, NQ, 192]
  attn_mfma_kernel<<<dim3((NQ + 63) / 64, BB * 2), 256, 0, stream>>>(qbuf, kbuf, vbuf, obb);
  // 5) x1 = maxpool_skip(x)
  maxpool_kernel<<<(BB * NQ * 192 + 255) / 256, 256, 0, stream>>>(x, x1);
  // 6) x1 += obb @ proj_w + proj_b
  gemm_mfma_kernel<0, 1, float>
      <<<dim3(192 / 64, (M2 + 127) / 128), 256, 0, stream>>>(
          obb, proj_wT, proj_b, x1, M2, 192, 192, 192, 192);
  // 7) comb[:, 768:960] = LN(x1)  (bf16)
  ln_rows_bf16_kernel<<<(M2 + 3) / 4, 256, 0, stream>>>(x1, ln2_g, ln2_b, comb + 768, M2, 960);
  // 8) comb[:, 0:768] = gelu(xn2 @ fc1_w + fc1_b)  (bf16)
  gemm_mfma_kernel<1, 0, unsigned short>
      <<<dim3(HID / 64, (M2 + 127) / 128), 256, 0, stream>>>(
          comb + 768, fc1_wT, fc1_b, comb, M2, HID, 192, 960, 960);
  // 9+10) out = comb @ [fc2_w; projd_w] + (fc2_b + projd_b)   (K=960)
  gemm_mfma_kernel<0, 0, float>
      <<<dim3(DOUT / 64, (M2 + 127) / 128), 256, 0, stream>>>(
          comb, wcombT, bcomb, out, M2, DOUT, 960, 960, DOUT);
}

// Round 10
// 1189.844 us; speedup vs baseline: 2.1755x; 1.1297x over previous
//
#include <hip/hip_runtime.h>
#include <hip/hip_bf16.h>
#include <type_traits>

// ---------------- fixed problem dims ----------------
#define BB   16
#define N0   6273      // 1 + 8*28*28
#define NQ   1569      // 1 + 8*14*14
#define C3   576
#define HID  768
#define DOUT 384
#define M1   (BB*N0)   // 100368
#define M2   (BB*NQ)   // 25104

typedef __attribute__((ext_vector_type(8))) short  s16x8;
typedef __attribute__((ext_vector_type(8))) __bf16 bf16x8;
typedef __attribute__((ext_vector_type(4))) float  f32x4;

static __device__ __forceinline__ float bf2f(unsigned short u) {
  return __uint_as_float(((unsigned)u) << 16);
}
static __device__ __forceinline__ unsigned short f2bf(float f) {
  unsigned x = __float_as_uint(f);
  x += 0x7fffu + ((x >> 16) & 1u);   // RNE
  return (unsigned short)(x >> 16);
}
static __device__ __forceinline__ unsigned pk2(float a, float b) {
  return (unsigned)f2bf(a) | ((unsigned)f2bf(b) << 16);
}

// redistribute P: C/D key order (two 16-key sub-tiles, key=4hi+r) -> B-frag key
// order (32 consecutive keys, k=8hi+j). Validated end-to-end (rounds 4/9).
static __device__ __forceinline__ s16x8 redistP(const float* p0, const float* p1, int hi) {
  unsigned w00 = pk2(p0[0], p0[1]), w01 = pk2(p0[2], p0[3]);
  unsigned w10 = pk2(p1[0], p1[1]), w11 = pk2(p1[2], p1[3]);
  unsigned w00x = __shfl_xor(w00, 32), w01x = __shfl_xor(w01, 32);
  unsigned w10x = __shfl_xor(w10, 32), w11x = __shfl_xor(w11, 32);
  unsigned w00y = __shfl_xor(w00, 16), w01y = __shfl_xor(w01, 16);
  unsigned w10y = __shfl_xor(w10, 16), w11y = __shfl_xor(w11, 16);
  unsigned w00z = __shfl_xor(w00x, 16), w01z = __shfl_xor(w01x, 16);
  unsigned w10z = __shfl_xor(w10x, 16), w11z = __shfl_xor(w11x, 16);
  bool h0 = (hi == 0), h1 = (hi == 1), h2 = (hi == 2);
  union { unsigned u[4]; s16x8 v; } pf;
  pf.u[0] = h0 ? w00  : h1 ? w00z : h2 ? w10x : w10y;
  pf.u[1] = h0 ? w01  : h1 ? w01z : h2 ? w11x : w11y;
  pf.u[2] = h0 ? w00y : h1 ? w00x : h2 ? w10z : w10;
  pf.u[3] = h0 ? w01y : h1 ? w01x : h2 ? w11z : w11;
  return pf.v;
}

// ---------------- LayerNorm over D=192 -> bf16 out (ldc stride) ----------------
__global__ __launch_bounds__(256) void ln_rows_bf16_kernel(
    const float* __restrict__ in, const float* __restrict__ g,
    const float* __restrict__ bta, unsigned short* __restrict__ out,
    int rows, int ldc) {
  int row = blockIdx.x * 4 + (threadIdx.x >> 6);
  int lane = threadIdx.x & 63;
  if (row >= rows) return;                 // whole wave exits together
  const float* p = in + (size_t)row * 192;
  float v0 = p[lane], v1 = p[lane + 64], v2 = p[lane + 128];
  float s = v0 + v1 + v2;
  float q = v0 * v0 + v1 * v1 + v2 * v2;
  #pragma unroll
  for (int m = 32; m; m >>= 1) { s += __shfl_xor(s, m, 64); q += __shfl_xor(q, m, 64); }
  float mean = s * (1.f / 192.f);
  float var  = q * (1.f / 192.f) - mean * mean;
  float rstd = rsqrtf(var + 1e-5f);
  unsigned short* po = out + (size_t)row * ldc;
  po[lane]       = f2bf((v0 - mean) * rstd * g[lane]       + bta[lane]);
  po[lane + 64]  = f2bf((v1 - mean) * rstd * g[lane + 64]  + bta[lane + 64]);
  po[lane + 128] = f2bf((v2 - mean) * rstd * g[lane + 128] + bta[lane + 128]);
}

// ---------------- weight prep: fp32 [K][N] -> bf16 [N][K] ----------------
__global__ __launch_bounds__(256) void wtrans_kernel(
    const float* __restrict__ in, unsigned short* __restrict__ out, int K, int N) {
  int idx = blockIdx.x * 256 + threadIdx.x;
  if (idx >= K * N) return;
  int n = idx / K, k = idx - n * K;
  out[idx] = f2bf(in[k * N + n]);
}

// combined [fc2_w; projd_w] -> bf16 [384][960], bias sum -> bc[384]
__global__ __launch_bounds__(256) void wcomb_kernel(
    const float* __restrict__ fc2w, const float* __restrict__ projdw,
    const float* __restrict__ fc2b, const float* __restrict__ projdb,
    unsigned short* __restrict__ wT, float* __restrict__ bc) {
  int idx = blockIdx.x * 256 + threadIdx.x;
  if (idx < 384 * 960) {
    int n = idx / 960, k = idx - n * 960;
    float v = (k < 768) ? fc2w[k * 384 + n] : projdw[(k - 768) * 384 + n];
    wT[idx] = f2bf(v);
  }
  if (idx < 384) bc[idx] = fc2b[idx] + projdb[idx];
}

// ---------------- MFMA GEMM: C[M][N] = act(A[M][K]bf16 @ BT[N][K]^T + bias) (+C)
// BM=128 BN=64 BK=64, 256 thr / 4 waves, wave tile 32(m) x 64(n).
// LDS XOR swizzle: byte(row, cb) = row*128 + ((cb ^ (row&7)) << 4), cb in 0..7.
template <int ACT, int BETA, typename TC>
__global__ __launch_bounds__(256) void gemm_mfma_kernel(
    const unsigned short* __restrict__ A, const unsigned short* __restrict__ BT,
    const float* __restrict__ bias, TC* __restrict__ C,
    int M, int N, int K, int lda, int ldc) {
  __shared__ alignas(16) unsigned short As[128 * 64];   // 16 KB
  __shared__ alignas(16) unsigned short Bs[64 * 64];    //  8 KB
  const int tid = threadIdx.x;
  const int lane = tid & 63, wid = tid >> 6;
  const int lo = lane & 15, hi = lane >> 4;
  const int bm = blockIdx.y * 128;
  const int bn = blockIdx.x * 64;
  const int s_row = tid >> 3;        // 0..31
  const int s_cb  = tid & 7;         // 0..7
  const int wrow  = wid * 32;
  char* asb = (char*)As;
  char* bsb = (char*)Bs;
  f32x4 acc[2][4];
  #pragma unroll
  for (int mi = 0; mi < 2; ++mi)
    #pragma unroll
    for (int nj = 0; nj < 4; ++nj) {
      acc[mi][nj][0] = 0.f; acc[mi][nj][1] = 0.f;
      acc[mi][nj][2] = 0.f; acc[mi][nj][3] = 0.f;
    }
  for (int k0 = 0; k0 < K; k0 += 64) {
    uint4 av[4], bv[2];
    #pragma unroll
    for (int i = 0; i < 4; ++i) {
      int row = s_row + 32 * i;
      int rg = bm + row; if (rg > M - 1) rg = M - 1;
      av[i] = *(const uint4*)(A + (size_t)rg * lda + k0 + s_cb * 8);
    }
    #pragma unroll
    for (int i = 0; i < 2; ++i) {
      int col = s_row + 32 * i;
      bv[i] = *(const uint4*)(BT + (size_t)(bn + col) * K + k0 + s_cb * 8);
    }
    if (k0) __syncthreads();           // prev compute done before overwrite
    #pragma unroll
    for (int i = 0; i < 4; ++i) {
      int row = s_row + 32 * i;
      *(uint4*)(asb + row * 128 + ((s_cb ^ (row & 7)) << 4)) = av[i];
    }
    #pragma unroll
    for (int i = 0; i < 2; ++i) {
      int col = s_row + 32 * i;
      *(uint4*)(bsb + col * 128 + ((s_cb ^ (col & 7)) << 4)) = bv[i];
    }
    __syncthreads();
    #pragma unroll
    for (int ks = 0; ks < 2; ++ks) {
      s16x8 af[2], bf[4];
      #pragma unroll
      for (int mi = 0; mi < 2; ++mi) {
        int row = wrow + mi * 16 + lo;
        af[mi] = *(const s16x8*)(asb + row * 128 + (((ks * 4 + hi) ^ (row & 7)) << 4));
      }
      #pragma unroll
      for (int nj = 0; nj < 4; ++nj) {
        int col = nj * 16 + lo;
        bf[nj] = *(const s16x8*)(bsb + col * 128 + (((ks * 4 + hi) ^ (col & 7)) << 4));
      }
      #pragma unroll
      for (int mi = 0; mi < 2; ++mi)
        #pragma unroll
        for (int nj = 0; nj < 4; ++nj)
          acc[mi][nj] = __builtin_amdgcn_mfma_f32_16x16x32_bf16(
              (bf16x8)af[mi], (bf16x8)bf[nj], acc[mi][nj], 0, 0, 0);
    }
  }
  // epilogue: D col = lo, row = 4*hi + r
  #pragma unroll
  for (int nj = 0; nj < 4; ++nj) {
    float bsv = bias[bn + nj * 16 + lo];
    #pragma unroll
    for (int mi = 0; mi < 2; ++mi) {
      int rowb = bm + wrow + mi * 16 + hi * 4;
      #pragma unroll
      for (int r = 0; r < 4; ++r) {
        int row = rowb + r;
        if (row >= M) continue;
        float v = acc[mi][nj][r] + bsv;
        if (ACT == 1) v = 0.5f * v * (1.f + erff(v * 0.70710678118654752f));
        size_t oi = (size_t)row * ldc + bn + nj * 16 + lo;
        if constexpr (BETA != 0) {
          if constexpr (std::is_same<TC, float>::value) v += C[oi];
          else v += bf2f(C[oi]);
        }
        if constexpr (std::is_same<TC, float>::value) C[oi] = v;
        else C[oi] = f2bf(v);
      }
    }
  }
}

// ---------------- depthwise conv3d (3x3x3, stride 1,2,2, pad 1) + LN over hd=96 ---
// wave-shuffle reduction (2 barriers instead of 14)
__global__ __launch_bounds__(128) void pool_ln_kernel(
    const unsigned short* __restrict__ qkv, const float* __restrict__ w,
    const float* __restrict__ g, const float* __restrict__ bb,
    unsigned short* __restrict__ outp, int cidx, float oscale) {
  const int bid = blockIdx.x;
  const int l  = bid % NQ;
  const int bh = bid / NQ;
  const int h  = bh & 1;
  const int b  = bh >> 1;
  const int d  = threadIdx.x;
  float val = 0.f;
  if (d < 96) {
    const unsigned short* base = qkv + (size_t)b * N0 * C3 + cidx * 192 + h * 96 + d;
    if (l == 0) {
      val = bf2f(base[0]);                          // cls token (n = 0)
    } else {
      int lp = l - 1;
      int to = lp / 196;
      int rem = lp - to * 196;
      int ho = rem / 14;
      int wo = rem - ho * 14;
      const float* wd = w + d * 27;
      #pragma unroll
      for (int kt = 0; kt < 3; ++kt) {
        int it = to + kt - 1;
        if ((unsigned)it >= 8u) continue;
        #pragma unroll
        for (int kh = 0; kh < 3; ++kh) {
          int ih = 2 * ho + kh - 1;
          if ((unsigned)ih >= 28u) continue;
          #pragma unroll
          for (int kw = 0; kw < 3; ++kw) {
            int iw = 2 * wo + kw - 1;
            if ((unsigned)iw >= 28u) continue;
            int n = 1 + (it * 28 + ih) * 28 + iw;
            val += wd[(kt * 3 + kh) * 3 + kw] * bf2f(base[(size_t)n * C3]);
          }
        }
      }
    }
  }
  const int lane = d & 63, wv = d >> 6;
  float s1 = (d < 96) ? val : 0.f;
  float s2 = (d < 96) ? val * val : 0.f;
  #pragma unroll
  for (int mm = 32; mm; mm >>= 1) {
    s1 += __shfl_xor(s1, mm, 64);
    s2 += __shfl_xor(s2, mm, 64);
  }
  __shared__ float wsum[4];
  if (lane == 0) { wsum[wv] = s1; wsum[2 + wv] = s2; }
  __syncthreads();
  float S  = wsum[0] + wsum[1];
  float Q2 = wsum[2] + wsum[3];
  float mean = S * (1.f / 96.f);
  float rstd = rsqrtf(Q2 * (1.f / 96.f) - mean * mean + 1e-5f);
  if (d < 96)
    outp[((size_t)bh * NQ + l) * 96 + d] =
        f2bf(((val - mean) * rstd * g[d] + bb[d]) * oscale);
}

// ---------------- MFMA flash attention (bf16, 16x16x32), KC=64, bf16 out --------
// Swapped QK^T: S^T = mfma(K, Q) -> lane holds scores for q = lane&15.
// Swapped PV:   O^T = mfma(V^T, P^T) -> softmax state lane-local.
// Vt swizzle: byte(d,k) = (d*128 + 2k) ^ (g(d)<<4), g = ((d>>1)^(d>>4))&7.
//   writes (d=2*c2): g = (c2^(c2>>3))&7 -> spreads 48 scatter lanes over 8 groups
//   reads  (d=16t+lo): g = ((lo>>1)&7)^(t&7) -> 8 groups x2 lanes = 2-way (free)
__global__ __launch_bounds__(256) void attn_mfma_kernel(
    const unsigned short* __restrict__ qb, const unsigned short* __restrict__ kb,
    const unsigned short* __restrict__ vb, unsigned short* __restrict__ o) {
  __shared__ alignas(16) unsigned short Ks[64][104];   // [key][d], 13312 B
  __shared__ alignas(16) unsigned short Vt[96 * 64];   // [d][key] swizzled, 12288 B
  const int tid  = threadIdx.x;
  const int lane = tid & 63;
  const int wid  = tid >> 6;
  const int lo = lane & 15, hi = lane >> 4;
  const int bh = blockIdx.y;
  const int b = bh >> 1, h = bh & 1;
  const int q0 = blockIdx.x * 64 + wid * 16;
  const int qg = q0 + lo;

  const unsigned short* qbase = qb + (size_t)bh * NQ * 96;
  const unsigned short* kbase = kb + (size_t)bh * NQ * 96;
  const unsigned short* vbase = vb + (size_t)bh * NQ * 96;
  char* vtb = (char*)Vt;

  s16x8 qf[3];
  if (qg < NQ) {
    const unsigned short* qrow = qbase + (size_t)qg * 96 + hi * 8;
    qf[0] = *(const s16x8*)(qrow);
    qf[1] = *(const s16x8*)(qrow + 32);
    qf[2] = *(const s16x8*)(qrow + 64);
  } else {
    #pragma unroll
    for (int j = 0; j < 8; ++j) { qf[0][j] = 0; qf[1][j] = 0; qf[2][j] = 0; }
  }

  f32x4 ot[6];
  #pragma unroll
  for (int t = 0; t < 6; ++t) { ot[t][0] = 0.f; ot[t][1] = 0.f; ot[t][2] = 0.f; ot[t][3] = 0.f; }
  float m = -1e30f, lsum = 0.f;

  const int nchunks = (NQ + 63) / 64;   // 25
  for (int c = 0; c < nchunks; ++c) {
    const int k0 = c * 64;
    // ---- stage K [64][96] bf16 (3072 uints) ----
    #pragma unroll
    for (int j = 0; j < 12; ++j) {
      int u = tid + 256 * j;
      int kr = u / 48, c2 = u - kr * 48;
      unsigned val = 0;
      if (k0 + kr < NQ)
        val = *(const unsigned*)(kbase + (size_t)(k0 + kr) * 96 + c2 * 2);
      *(unsigned*)(&Ks[kr][c2 * 2]) = val;
    }
    // ---- stage V transposed + swizzled ----
    #pragma unroll
    for (int j = 0; j < 12; ++j) {
      int u = tid + 256 * j;
      int kr = u / 48, c2 = u - kr * 48;
      unsigned val = 0;
      if (k0 + kr < NQ)
        val = *(const unsigned*)(vbase + (size_t)(k0 + kr) * 96 + c2 * 2);
      int d0 = c2 * 2, d1 = d0 + 1;
      int gsw = ((d0 >> 1) ^ (d0 >> 4)) & 7;   // same for d1
      int o0 = (d0 * 128 + kr * 2) ^ (gsw << 4);
      int o1 = (d1 * 128 + kr * 2) ^ (gsw << 4);
      *(unsigned short*)(vtb + o0) = (unsigned short)(val & 0xffffu);
      *(unsigned short*)(vtb + o1) = (unsigned short)(val >> 16);
    }
    __syncthreads();
    // ---- S^T = K · Q^T : 4 sub-tiles of 16 keys ----
    f32x4 st[4];
    #pragma unroll
    for (int s = 0; s < 4; ++s) { st[s][0] = 0.f; st[s][1] = 0.f; st[s][2] = 0.f; st[s][3] = 0.f; }
    #pragma unroll
    for (int cc = 0; cc < 3; ++cc) {
      #pragma unroll
      for (int s = 0; s < 4; ++s) {
        s16x8 kf = *(const s16x8*)(&Ks[s * 16 + lo][cc * 32 + hi * 8]);
        st[s] = __builtin_amdgcn_mfma_f32_16x16x32_bf16((bf16x8)kf, (bf16x8)qf[cc], st[s], 0, 0, 0);
      }
    }
    if (k0 + 64 > NQ) {   // mask OOB keys (last chunk only)
      #pragma unroll
      for (int s = 0; s < 4; ++s)
        #pragma unroll
        for (int r = 0; r < 4; ++r)
          if (k0 + s * 16 + 4 * hi + r >= NQ) st[s][r] = -1e30f;
    }
    // ---- online softmax (q = lo; partner lanes differ in bits 4,5) ----
    float mc = -1e30f;
    #pragma unroll
    for (int s = 0; s < 4; ++s)
      #pragma unroll
      for (int r = 0; r < 4; ++r) mc = fmaxf(mc, st[s][r]);
    mc = fmaxf(mc, __shfl_xor(mc, 16));
    mc = fmaxf(mc, __shfl_xor(mc, 32));
    if (!__all(mc <= m)) {           // defer-max
      float mnew = fmaxf(m, mc);
      float alpha = __expf(m - mnew);
      #pragma unroll
      for (int t = 0; t < 6; ++t) {
        ot[t][0] *= alpha; ot[t][1] *= alpha; ot[t][2] *= alpha; ot[t][3] *= alpha;
      }
      lsum *= alpha;
      m = mnew;
    }
    float p[4][4];
    float sum = 0.f;
    #pragma unroll
    for (int s = 0; s < 4; ++s)
      #pragma unroll
      for (int r = 0; r < 4; ++r) {
        p[s][r] = __expf(st[s][r] - m);
        sum += p[s][r];
      }
    sum += __shfl_xor(sum, 16);
    sum += __shfl_xor(sum, 32);
    lsum += sum;
    s16x8 pf01 = redistP(p[0], p[1], hi);   // keys  0..31
    s16x8 pf23 = redistP(p[2], p[3], hi);   // keys 32..63
    // ---- O^T += V^T · P^T  (6 d-tiles x 2 key-halves) ----
    #pragma unroll
    for (int t = 0; t < 6; ++t) {
      int d = 16 * t + lo;
      int gsw = ((d >> 1) ^ (d >> 4)) & 7;
      int base = d * 128 + hi * 16;
      s16x8 va0 = *(const s16x8*)(vtb + ((base)      ^ (gsw << 4)));
      s16x8 va1 = *(const s16x8*)(vtb + ((base + 64) ^ (gsw << 4)));
      ot[t] = __builtin_amdgcn_mfma_f32_16x16x32_bf16((bf16x8)va0, (bf16x8)pf01, ot[t], 0, 0, 0);
      ot[t] = __builtin_amdgcn_mfma_f32_16x16x32_bf16((bf16x8)va1, (bf16x8)pf23, ot[t], 0, 0, 0);
    }
    __syncthreads();
  }
  if (qg < NQ) {
    float invl = 1.f / lsum;
    unsigned short* po = o + ((size_t)b * NQ + qg) * 192 + h * 96 + hi * 4;
    #pragma unroll
    for (int t = 0; t < 6; ++t) {
      ushort4 u4;
      u4.x = f2bf(ot[t][0] * invl); u4.y = f2bf(ot[t][1] * invl);
      u4.z = f2bf(ot[t][2] * invl); u4.w = f2bf(ot[t][3] * invl);
      *(ushort4*)(po + 16 * t) = u4;
    }
  }
}

// ---------------- maxpool (1,3,3)/(1,2,2)/pad(0,1,1) skip path -> x1 -------------
__global__ __launch_bounds__(256) void maxpool_kernel(
    const float* __restrict__ x, float* __restrict__ x1) {
  int idx = blockIdx.x * 256 + threadIdx.x;
  const int total = BB * NQ * 192;
  if (idx >= total) return;
  int cc = idx % 192;
  int rem = idx / 192;
  int l = rem % NQ;
  int b = rem / NQ;
  const float* xb = x + (size_t)b * N0 * 192;
  float m;
  if (l == 0) {
    m = xb[cc];
  } else {
    int lp = l - 1;
    int to = lp / 196;
    int r2 = lp - to * 196;
    int ho = r2 / 14;
    int wo = r2 - ho * 14;
    m = -INFINITY;
    #pragma unroll
    for (int kh = 0; kh < 3; ++kh) {
      int ih = 2 * ho + kh - 1;
      if ((unsigned)ih >= 28u) continue;
      #pragma unroll
      for (int kw = 0; kw < 3; ++kw) {
        int iw = 2 * wo + kw - 1;
        if ((unsigned)iw >= 28u) continue;
        int n = 1 + (to * 28 + ih) * 28 + iw;
        m = fmaxf(m, xb[(size_t)n * 192 + cc]);
      }
    }
  }
  x1[idx] = m;
}

// ---------------- launch ----------------
extern "C" void kernel_launch(void* const* d_in, const int* in_sizes, int n_in,
                              void* d_out, int out_size, void* d_ws, size_t ws_size,
                              hipStream_t stream) {
  (void)in_sizes; (void)n_in; (void)out_size; (void)ws_size;
  const float* x       = (const float*)d_in[0];
  const float* ln1_g   = (const float*)d_in[1];
  const float* ln1_b   = (const float*)d_in[2];
  const float* qkv_w   = (const float*)d_in[3];
  const float* qkv_b   = (const float*)d_in[4];
  const float* pq_w    = (const float*)d_in[5];
  const float* pk_w    = (const float*)d_in[6];
  const float* pv_w    = (const float*)d_in[7];
  const float* nq_g    = (const float*)d_in[8];
  const float* nq_b    = (const float*)d_in[9];
  const float* nk_g    = (const float*)d_in[10];
  const float* nk_b    = (const float*)d_in[11];
  const float* nv_g    = (const float*)d_in[12];
  const float* nv_b    = (const float*)d_in[13];
  const float* proj_w  = (const float*)d_in[14];
  const float* proj_b  = (const float*)d_in[15];
  const float* ln2_g   = (const float*)d_in[16];
  const float* ln2_b   = (const float*)d_in[17];
  const float* fc1_w   = (const float*)d_in[18];
  const float* fc1_b   = (const float*)d_in[19];
  const float* fc2_w   = (const float*)d_in[20];
  const float* fc2_b   = (const float*)d_in[21];
  const float* projd_w = (const float*)d_in[22];
  const float* projd_b = (const float*)d_in[23];

  // ---- workspace layout (bytes), total ~155.5 MB ----
  char* ws = (char*)d_ws;
  // region 1: xnb [M1][192] bf16 (38,541,312 B); reused for pooled q/k/v bf16
  unsigned short* xnb  = (unsigned short*)(ws);
  unsigned short* qbuf = (unsigned short*)(ws);
  unsigned short* kbuf = (unsigned short*)(ws + 9639936);
  unsigned short* vbuf = (unsigned short*)(ws + 19279872);
  // region 2: qkvb [M1][576] bf16 (115,623,936 B); reused after pooling:
  char* r2 = ws + 38541312;
  unsigned short* qkvb = (unsigned short*)(r2);
  unsigned short* obb  = (unsigned short*)(r2);               //  9,639,936 B
  float*          x1   = (float*)(r2 + 9639936);              // 19,279,872 B
  unsigned short* comb = (unsigned short*)(r2 + 28919808);    // 48,199,680 B [M2][960]
  // region 3: prepped weights (after 38,541,312 + 115,623,936 = 154,165,248)
  char* r3 = ws + 154165248;
  unsigned short* qkv_wT  = (unsigned short*)(r3);            // [576][192] 221,184 B
  unsigned short* proj_wT = (unsigned short*)(r3 + 221184);   // [192][192]  73,728 B
  unsigned short* fc1_wT  = (unsigned short*)(r3 + 294912);   // [768][192] 294,912 B
  unsigned short* wcombT  = (unsigned short*)(r3 + 589824);   // [384][960] 737,280 B
  float*          bcomb   = (float*)(r3 + 1327104);           //  1,536 B
  float* out = (float*)d_out;

  const float scale = 0.10206207261596577f;  // 1/sqrt(96), folded into Q

  // 0) weight prep
  wtrans_kernel<<<(576 * 192 + 255) / 256, 256, 0, stream>>>(qkv_w, qkv_wT, 192, 576);
  wtrans_kernel<<<(192 * 192 + 255) / 256, 256, 0, stream>>>(proj_w, proj_wT, 192, 192);
  wtrans_kernel<<<(768 * 192 + 255) / 256, 256, 0, stream>>>(fc1_w, fc1_wT, 192, 768);
  wcomb_kernel<<<(384 * 960 + 255) / 256, 256, 0, stream>>>(fc2_w, projd_w, fc2_b, projd_b,
                                                            wcombT, bcomb);
  // 1) xnb = LN(x)  (bf16)
  ln_rows_bf16_kernel<<<(M1 + 3) / 4, 256, 0, stream>>>(x, ln1_g, ln1_b, xnb, M1, 192);
  // 2) qkv = xnb @ qkv_w + qkv_b  (bf16)
  gemm_mfma_kernel<0, 0, unsigned short>
      <<<dim3(C3 / 64, (M1 + 127) / 128), 256, 0, stream>>>(
          xnb, qkv_wT, qkv_b, qkvb, M1, C3, 192, 192, C3);
  // 3) pooled+LN q, k, v  (bf16; q pre-scaled)
  pool_ln_kernel<<<BB * 2 * NQ, 128, 0, stream>>>(qkvb, pq_w, nq_g, nq_b, qbuf, 0, scale);
  pool_ln_kernel<<<BB * 2 * NQ, 128, 0, stream>>>(qkvb, pk_w, nk_g, nk_b, kbuf, 1, 1.f);
  pool_ln_kernel<<<BB * 2 * NQ, 128, 0, stream>>>(qkvb, pv_w, nv_g, nv_b, vbuf, 2, 1.f);
  // 4) o = softmax(qk^T) v  (MFMA flash, KC=64) -> bf16 [B, NQ, 192]
  attn_mfma_kernel<<<dim3((NQ + 63) / 64, BB * 2), 256, 0, stream>>>(qbuf, kbuf, vbuf, obb);
  // 5) x1 = maxpool_skip(x)
  maxpool_kernel<<<(BB * NQ * 192 + 255) / 256, 256, 0, stream>>>(x, x1);
  // 6) x1 += obb @ proj_w + proj_b
  gemm_mfma_kernel<0, 1, float>
      <<<dim3(192 / 64, (M2 + 127) / 128), 256, 0, stream>>>(
          obb, proj_wT, proj_b, x1, M2, 192, 192, 192, 192);
  // 7) comb[:, 768:960] = LN(x1)  (bf16)
  ln_rows_bf16_kernel<<<(M2 + 3) / 4, 256, 0, stream>>>(x1, ln2_g, ln2_b, comb + 768, M2, 960);
  // 8) comb[:, 0:768] = gelu(xn2 @ fc1_w + fc1_b)  (bf16)
  gemm_mfma_kernel<1, 0, unsigned short>
      <<<dim3(HID / 64, (M2 + 127) / 128), 256, 0, stream>>>(
          comb + 768, fc1_wT, fc1_b, comb, M2, HID, 192, 960, 960);
  // 9+10) out = comb @ [fc2_w; projd_w] + (fc2_b + projd_b)   (K=960)
  gemm_mfma_kernel<0, 0, float>
      <<<dim3(DOUT / 64, (M2 + 127) / 128), 256, 0, stream>>>(
          comb, wcombT, bcomb, out, M2, DOUT, 960, 960, DOUT);
}